// Round 1
// baseline (995.347 us; speedup 1.0000x reference)
//
#include <hip/hip_runtime.h>

// ---- problem constants --------------------------------------------------
static constexpr int OMODE = 2, PMODE = 4, NZ = 8;
static constexpr int NYX = 512;   // object plane 512x512
static constexpr int NP  = 128;   // probe / tile 128x128
static constexpr int BATCH = 64;
static constexpr int LSTR = 129;  // padded LDS line stride (floats)
static constexpr float INV_N2 = 1.0f / 16384.0f;   // 1/(128*128) ifft2 norm

__device__ __forceinline__ int br7(int x) { return (int)(__brev((unsigned)x) >> 25); }

// Per-thread twiddle state. Indexed only with compile-time constants
// (unrolled loops) -> stays in VGPRs.
struct Tw {
  float tc[7], ts[7];        // cos/sin(pi*j/h), j=lane&(h-1), h=1<<s (s=6 -> h=64)
  float g[6];                // +1 for lower lane of pair, -1 for upper
  float dwr[6], dwi[6];      // DIF post-mul: up ? conj(w) : 1
  float swr[6], swi[6];      // DIT pre-mul : up ? w       : 1
};

__device__ __forceinline__ void cmul(float2& a, float br_, float bi_) {
  float x = a.x * br_ - a.y * bi_;
  a.y = a.x * bi_ + a.y * br_;
  a.x = x;
}

// Forward 128-pt DIF across 64 lanes, 2 complex/lane (slots: lane, lane+64).
// Natural-order input -> bit-reversed-order output slots.
__device__ __forceinline__ void dif128(float2& A, float2& B, const Tw& tw) {
  { // register stage h=64: w = e^{-i*pi*lane/64}
    float dr = A.x - B.x, di = A.y - B.y;
    A.x += B.x; A.y += B.y;
    B.x = dr * tw.tc[6] + di * tw.ts[6];
    B.y = di * tw.tc[6] - dr * tw.ts[6];
  }
#pragma unroll
  for (int s = 5; s >= 0; --s) {
    const int h = 1 << s;
    float tx, ty, dx, dy;
    tx = __shfl_xor(A.x, h); ty = __shfl_xor(A.y, h);
    dx = tx + tw.g[s] * A.x; dy = ty + tw.g[s] * A.y;
    A.x = dx * tw.dwr[s] - dy * tw.dwi[s];
    A.y = dx * tw.dwi[s] + dy * tw.dwr[s];
    tx = __shfl_xor(B.x, h); ty = __shfl_xor(B.y, h);
    dx = tx + tw.g[s] * B.x; dy = ty + tw.g[s] * B.y;
    B.x = dx * tw.dwr[s] - dy * tw.dwi[s];
    B.y = dx * tw.dwi[s] + dy * tw.dwr[s];
  }
}

// Inverse (unnormalized) 128-pt DIT: bit-reversed input slots -> natural output.
__device__ __forceinline__ void dit128(float2& A, float2& B, const Tw& tw) {
#pragma unroll
  for (int s = 0; s < 6; ++s) {
    const int h = 1 << s;
    float mx, my, tx, ty;
    mx = A.x * tw.swr[s] - A.y * tw.swi[s];
    my = A.x * tw.swi[s] + A.y * tw.swr[s];
    tx = __shfl_xor(mx, h); ty = __shfl_xor(my, h);
    A.x = tx + tw.g[s] * mx; A.y = ty + tw.g[s] * my;
    mx = B.x * tw.swr[s] - B.y * tw.swi[s];
    my = B.x * tw.swi[s] + B.y * tw.swr[s];
    tx = __shfl_xor(mx, h); ty = __shfl_xor(my, h);
    B.x = tx + tw.g[s] * mx; B.y = ty + tw.g[s] * my;
  }
  { // register stage h=64: w = e^{+i*pi*lane/64}
    float mx = B.x * tw.tc[6] - B.y * tw.ts[6];
    float my = B.x * tw.ts[6] + B.y * tw.tc[6];
    B.x = A.x - mx; B.y = A.y - my;
    A.x += mx; A.y += my;
  }
}

// Pre-scramble H into workspace: hp[px][py] = H[br(py)][br(px)] * (1/N^2).
__global__ void __launch_bounds__(256) init_hpre(const float* __restrict__ H,
                                                 float2* __restrict__ hp) {
  int i = blockIdx.x * blockDim.x + threadIdx.x;
  if (i >= NP * NP) return;
  int px = i >> 7, py = i & (NP - 1);
  int ky = br7(py), kx = br7(px);
  hp[px * NP + py] = make_float2(H[(ky * NP + kx) * 2 + 0] * INV_N2,
                                 H[(ky * NP + kx) * 2 + 1] * INV_N2);
}

__global__ void __launch_bounds__(512) ptycho_chain(
    const float* __restrict__ obja, const float* __restrict__ objp,
    const float* __restrict__ probe, const float* __restrict__ shifts,
    const float* __restrict__ H, const float2* __restrict__ hpre,
    const float* __restrict__ occu, const int* __restrict__ indices,
    const int* __restrict__ crop, float* __restrict__ dp, int use_hpre)
{
  extern __shared__ float lds[];
  float* RE = lds;
  float* IM = lds + NP * LSTR;

  const int blk  = blockIdx.x;           // n*8 + o*4 + p
  const int n    = blk >> 3;
  const int o    = (blk >> 2) & 1;
  const int p    = blk & 3;
  const int tid  = threadIdx.x;
  const int wid  = tid >> 6;             // 8 waves
  const int lane = tid & 63;

  const int   pos = indices[n];
  const int   cy  = crop[2 * pos + 0];
  const int   cx  = crop[2 * pos + 1];
  const float sh0 = shifts[2 * pos + 0];
  const float sh1 = shifts[2 * pos + 1];
  const float wocc = occu[o];

  // ---- twiddles (per-thread, reused by every line) ----------------------
  Tw tw;
#pragma unroll
  for (int s = 0; s < 7; ++s) {
    int h = 1 << s;
    int j = lane & (h - 1);
    float ang = 3.14159265358979f * (float)j / (float)h;  // 2*pi*j/(2h)
    __sincosf(ang, &tw.ts[s], &tw.tc[s]);
  }
#pragma unroll
  for (int s = 0; s < 6; ++s) {
    bool up = (lane >> s) & 1;
    tw.g[s]   = up ? -1.f : 1.f;
    tw.dwr[s] = up ? tw.tc[s] : 1.f;
    tw.dwi[s] = up ? -tw.ts[s] : 0.f;
    tw.swr[s] = up ? tw.tc[s] : 1.f;
    tw.swi[s] = up ? tw.ts[s] : 0.f;
  }

  // fftfreq at bit-reversed slot positions for this lane's two slots
  float fy0, fy1;
  {
    int k0 = br7(lane);                 // even
    fy0 = (float)(k0 < 64 ? k0 : k0 - 128) * (1.f / 128.f);
    int k1 = k0 + 1;                    // br7(lane+64)
    fy1 = (float)(k1 < 64 ? k1 : k1 - 128) * (1.f / 128.f);
  }

  // ---- phase P0: load probe rows + forward row FFT ----------------------
  const float2* probe2 = (const float2*)probe;
#pragma unroll 2
  for (int k = 0; k < 16; ++k) {
    int r = (wid << 4) + k;
    float2 A = probe2[(p * NP + r) * NP + lane];
    float2 B = probe2[(p * NP + r) * NP + lane + 64];
    dif128(A, B, tw);
    int base = r * LSTR;
    RE[base + lane]      = A.x; IM[base + lane]      = A.y;
    RE[base + lane + 64] = B.x; IM[base + lane + 64] = B.y;
  }
  __syncthreads();

  // ---- column phase: Fcol, freq-domain multiply, invCol -----------------
  // mode 0 = shift ramp (incl 1/N^2), mode 1 = H (hpre incl 1/N^2)
  auto cphase = [&](int mode) {
#pragma unroll 2
    for (int k = 0; k < 16; ++k) {
      int c = (wid << 4) + k;
      float2 A, B;
      A.x = RE[lane * LSTR + c];        A.y = IM[lane * LSTR + c];
      B.x = RE[(lane + 64) * LSTR + c]; B.y = IM[(lane + 64) * LSTR + c];
      dif128(A, B, tw);
      if (mode == 0) {
        int kxc = br7(c);
        float fx = (float)(kxc < 64 ? kxc : kxc - 128) * (1.f / 128.f);
        float com = fx * sh1;
        float s0, c0, s1, c1;
        __sincosf(-6.28318530717959f * (fy0 * sh0 + com), &s0, &c0);
        __sincosf(-6.28318530717959f * (fy1 * sh0 + com), &s1, &c1);
        cmul(A, c0 * INV_N2, s0 * INV_N2);
        cmul(B, c1 * INV_N2, s1 * INV_N2);
      } else if (use_hpre) {
        float2 h0 = hpre[c * NP + lane];
        float2 h1 = hpre[c * NP + lane + 64];
        cmul(A, h0.x, h0.y);
        cmul(B, h1.x, h1.y);
      } else {
        int kx = br7(c), ky0 = br7(lane);
        float hr0 = H[(ky0 * NP + kx) * 2], hi0 = H[(ky0 * NP + kx) * 2 + 1];
        float hr1 = H[((ky0 + 1) * NP + kx) * 2], hi1 = H[((ky0 + 1) * NP + kx) * 2 + 1];
        cmul(A, hr0 * INV_N2, hi0 * INV_N2);
        cmul(B, hr1 * INV_N2, hi1 * INV_N2);
      }
      dit128(A, B, tw);
      RE[lane * LSTR + c] = A.x;        IM[lane * LSTR + c] = A.y;
      RE[(lane + 64) * LSTR + c] = B.x; IM[(lane + 64) * LSTR + c] = B.y;
    }
    __syncthreads();
  };

  // ---- row phase: invRow, multiply by object slice T(z), Frow -----------
  auto rphase = [&](int z) {
#pragma unroll 2
    for (int k = 0; k < 16; ++k) {
      int r = (wid << 4) + k;
      int base = r * LSTR;
      float2 A, B;
      A.x = RE[base + lane];      A.y = IM[base + lane];
      B.x = RE[base + lane + 64]; B.y = IM[base + lane + 64];
      dit128(A, B, tw);
      size_t ob = ((size_t)(o * NZ + z) * NYX + (size_t)(cy + r)) * NYX + cx;
      float pa0 = obja[ob + lane],      ph0 = objp[ob + lane];
      float pa1 = obja[ob + lane + 64], ph1 = objp[ob + lane + 64];
      float s0, c0, s1, c1;
      __sincosf(ph0, &s0, &c0);
      __sincosf(ph1, &s1, &c1);
      cmul(A, pa0 * c0, pa0 * s0);
      cmul(B, pa1 * c1, pa1 * s1);
      dif128(A, B, tw);
      RE[base + lane]      = A.x; IM[base + lane]      = A.y;
      RE[base + lane + 64] = B.x; IM[base + lane + 64] = B.y;
    }
    __syncthreads();
  };

  cphase(0);        // Fcol + ramp + invCol  (completes probe shift)
  rphase(0);        // invRow + T0 + Frow
#pragma unroll 1
  for (int z = 1; z < NZ; ++z) {
    cphase(1);      // Fcol + H + invCol     (propagation z-1 -> z)
    rphase(z);      // invRow + Tz + Frow
  }

  // ---- final column FFT + |.|^2 accumulation ----------------------------
#pragma unroll 2
  for (int k = 0; k < 16; ++k) {
    int c = (wid << 4) + k;
    float2 A, B;
    A.x = RE[lane * LSTR + c];        A.y = IM[lane * LSTR + c];
    B.x = RE[(lane + 64) * LSTR + c]; B.y = IM[(lane + 64) * LSTR + c];
    dif128(A, B, tw);
    int brc = br7(c);
    int ky0 = br7(lane);
    float m0 = (A.x * A.x + A.y * A.y) * wocc;
    float m1 = (B.x * B.x + B.y * B.y) * wocc;
    atomicAdd(&dp[(size_t)n * (NP * NP) + ky0 * NP + brc], m0);
    atomicAdd(&dp[(size_t)n * (NP * NP) + (ky0 + 1) * NP + brc], m1);
  }
}

extern "C" void kernel_launch(void* const* d_in, const int* in_sizes, int n_in,
                              void* d_out, int out_size, void* d_ws, size_t ws_size,
                              hipStream_t stream) {
  const float* obja   = (const float*)d_in[0];
  const float* objp   = (const float*)d_in[1];
  const float* probe  = (const float*)d_in[2];
  const float* shifts = (const float*)d_in[3];
  const float* H      = (const float*)d_in[4];
  const float* occu   = (const float*)d_in[5];
  const int*   indices = (const int*)d_in[6];
  const int*   crop    = (const int*)d_in[7];
  float* dp = (float*)d_out;

  // output is accumulated with atomics -> zero it every call
  hipMemsetAsync(d_out, 0, (size_t)out_size * sizeof(float), stream);

  const size_t hpre_bytes = (size_t)NP * NP * sizeof(float2);
  int use_hpre = (ws_size >= hpre_bytes) ? 1 : 0;
  float2* hpre = (float2*)d_ws;
  if (use_hpre) {
    hipLaunchKernelGGL(init_hpre, dim3((NP * NP + 255) / 256), dim3(256), 0,
                       stream, H, hpre);
  }

  const int lds_bytes = 2 * NP * LSTR * (int)sizeof(float);  // 132096
  hipFuncSetAttribute((const void*)ptycho_chain,
                      hipFuncAttributeMaxDynamicSharedMemorySize, lds_bytes);
  hipLaunchKernelGGL(ptycho_chain, dim3(BATCH * OMODE * PMODE), dim3(512),
                     lds_bytes, stream,
                     obja, objp, probe, shifts, H, hpre, occu, indices, crop,
                     dp, use_hpre);
}

// Round 2
// 698.119 us; speedup vs baseline: 1.4258x; 1.4258x over previous
//
#include <hip/hip_runtime.h>

// ---- problem constants --------------------------------------------------
static constexpr int OMODE = 2, PMODE = 4, NZ = 8;
static constexpr int NYX = 512;   // object plane 512x512
static constexpr int NP  = 128;   // probe / tile 128x128
static constexpr int BATCH = 64;
static constexpr int LSTR = 129;  // padded LDS line stride (float2 units)
static constexpr int FSTR = 131;  // padded stride for the output reorder (floats)
static constexpr float INV_N2 = 1.0f / 16384.0f;   // 1/(128*128) ifft2 norm

__device__ __forceinline__ int br7(int x) { return (int)(__brev((unsigned)x) >> 25); }

// Per-thread twiddles, compile-time indexed only -> VGPRs. 32 floats.
struct Tw {
  float tc[7], ts[7];        // cos/sin(pi*j/h), j=lane&(h-1), h=1<<s
  float g[6];                // +1 lower lane of pair, -1 upper
  float dwr[6], dwi[6];      // DIF post-mul: up ? conj(w) : 1   (DIT uses dwr,-dwi)
};

__device__ __forceinline__ void cmul(float2& a, float br_, float bi_) {
  float x = a.x * br_ - a.y * bi_;
  a.y = a.x * bi_ + a.y * br_;
  a.x = x;
}

// Forward 128-pt DIF across 64 lanes, 2 complex/lane (slots: lane, lane+64).
// Natural-order input -> bit-reversed-order output slots.
__device__ __forceinline__ void dif128(float2& A, float2& B, const Tw& tw) {
  { // register stage h=64: w = e^{-i*pi*lane/64}
    float dr = A.x - B.x, di = A.y - B.y;
    A.x += B.x; A.y += B.y;
    B.x = dr * tw.tc[6] + di * tw.ts[6];
    B.y = di * tw.tc[6] - dr * tw.ts[6];
  }
#pragma unroll
  for (int s = 5; s >= 0; --s) {
    const int h = 1 << s;
    float tx, ty, dx, dy;
    tx = __shfl_xor(A.x, h); ty = __shfl_xor(A.y, h);
    dx = tx + tw.g[s] * A.x; dy = ty + tw.g[s] * A.y;
    A.x = dx * tw.dwr[s] - dy * tw.dwi[s];
    A.y = dx * tw.dwi[s] + dy * tw.dwr[s];
    tx = __shfl_xor(B.x, h); ty = __shfl_xor(B.y, h);
    dx = tx + tw.g[s] * B.x; dy = ty + tw.g[s] * B.y;
    B.x = dx * tw.dwr[s] - dy * tw.dwi[s];
    B.y = dx * tw.dwi[s] + dy * tw.dwr[s];
  }
}

// Inverse (unnormalized) 128-pt DIT: bit-reversed input slots -> natural output.
// swr == dwr, swi == -dwi (signs inlined).
__device__ __forceinline__ void dit128(float2& A, float2& B, const Tw& tw) {
#pragma unroll
  for (int s = 0; s < 6; ++s) {
    const int h = 1 << s;
    float mx, my, tx, ty;
    mx =  A.x * tw.dwr[s] + A.y * tw.dwi[s];
    my = -A.x * tw.dwi[s] + A.y * tw.dwr[s];
    tx = __shfl_xor(mx, h); ty = __shfl_xor(my, h);
    A.x = tx + tw.g[s] * mx; A.y = ty + tw.g[s] * my;
    mx =  B.x * tw.dwr[s] + B.y * tw.dwi[s];
    my = -B.x * tw.dwi[s] + B.y * tw.dwr[s];
    tx = __shfl_xor(mx, h); ty = __shfl_xor(my, h);
    B.x = tx + tw.g[s] * mx; B.y = ty + tw.g[s] * my;
  }
  { // register stage h=64: w = e^{+i*pi*lane/64}
    float mx = B.x * tw.tc[6] - B.y * tw.ts[6];
    float my = B.x * tw.ts[6] + B.y * tw.tc[6];
    B.x = A.x - mx; B.y = A.y - my;
    A.x += mx; A.y += my;
  }
}

// Pre-scramble H into workspace: hp[px][py] = H[br(py)][br(px)] * (1/N^2).
__global__ void __launch_bounds__(256) init_hpre(const float* __restrict__ H,
                                                 float2* __restrict__ hp) {
  int i = blockIdx.x * blockDim.x + threadIdx.x;
  if (i >= NP * NP) return;
  int px = i >> 7, py = i & (NP - 1);
  int ky = br7(py), kx = br7(px);
  hp[px * NP + py] = make_float2(H[(ky * NP + kx) * 2 + 0] * INV_N2,
                                 H[(ky * NP + kx) * 2 + 1] * INV_N2);
}

// Sum the 8 (o,p) partials per batch element.
__global__ void __launch_bounds__(256) reduce_dp(const float* __restrict__ part,
                                                 float* __restrict__ dp) {
  int i = blockIdx.x * 256 + threadIdx.x;
  if (i >= BATCH * NP * NP) return;
  int n = i >> 14;
  int r = i & (NP * NP - 1);
  const float* b = part + (size_t)n * 8 * (NP * NP) + r;
  float s = 0.f;
#pragma unroll
  for (int j = 0; j < 8; ++j) s += b[(size_t)j * (NP * NP)];
  dp[i] = s;
}

__global__ void __launch_bounds__(1024) ptycho_chain(
    const float* __restrict__ obja, const float* __restrict__ objp,
    const float* __restrict__ probe, const float* __restrict__ shifts,
    const float* __restrict__ H, const float2* __restrict__ hpre,
    const float* __restrict__ occu, const int* __restrict__ indices,
    const int* __restrict__ crop, float* __restrict__ dp,
    float* __restrict__ part, int use_hpre, int use_part)
{
  extern __shared__ float2 fld[];          // [128][LSTR] interleaved re/im
  float* fl = (float*)fld;                 // raw view for the output reorder

  const int blk  = blockIdx.x;             // n*8 + o*4 + p
  const int n    = blk >> 3;
  const int o    = (blk >> 2) & 1;
  const int p    = blk & 3;
  const int tid  = threadIdx.x;
  const int wid  = tid >> 6;               // 16 waves
  const int lane = tid & 63;

  const int   pos = indices[n];
  const int   cy  = crop[2 * pos + 0];
  const int   cx  = crop[2 * pos + 1];
  const float sh0 = shifts[2 * pos + 0];
  const float sh1 = shifts[2 * pos + 1];
  const float wocc = occu[o];

  // ---- twiddles ---------------------------------------------------------
  Tw tw;
#pragma unroll
  for (int s = 0; s < 7; ++s) {
    int h = 1 << s;
    int j = lane & (h - 1);
    float ang = 3.14159265358979f * (float)j / (float)h;
    __sincosf(ang, &tw.ts[s], &tw.tc[s]);
  }
#pragma unroll
  for (int s = 0; s < 6; ++s) {
    bool up = (lane >> s) & 1;
    tw.g[s]   = up ? -1.f : 1.f;
    tw.dwr[s] = up ? tw.tc[s] : 1.f;
    tw.dwi[s] = up ? -tw.ts[s] : 0.f;
  }

  // fftfreq at bit-reversed slot positions for this lane's two slots
  float fy0, fy1;
  {
    int k0 = br7(lane);                 // even
    fy0 = (float)(k0 < 64 ? k0 : k0 - 128) * (1.f / 128.f);
    int k1 = k0 + 1;
    fy1 = (float)(k1 < 64 ? k1 : k1 - 128) * (1.f / 128.f);
  }

  // ---- P0: load probe rows + forward row FFT ----------------------------
  const float2* probe2 = (const float2*)probe;
#pragma unroll
  for (int k0 = 0; k0 < 8; k0 += 4) {
    float2 A[4], B[4];
#pragma unroll
    for (int kk = 0; kk < 4; ++kk) {
      int r = wid * 8 + k0 + kk;
      A[kk] = probe2[(p * NP + r) * NP + lane];
      B[kk] = probe2[(p * NP + r) * NP + lane + 64];
    }
#pragma unroll
    for (int kk = 0; kk < 4; ++kk) dif128(A[kk], B[kk], tw);
#pragma unroll
    for (int kk = 0; kk < 4; ++kk) {
      int base = (wid * 8 + k0 + kk) * LSTR;
      fld[base + lane]      = A[kk];
      fld[base + lane + 64] = B[kk];
    }
  }
  __syncthreads();

  // ---- column phase: Fcol, freq multiply, invCol ------------------------
  auto cphase = [&](int mode) {
#pragma unroll
    for (int k0 = 0; k0 < 8; k0 += 4) {
      float2 h0[4], h1[4];
      if (mode == 1 && use_hpre) {
#pragma unroll
        for (int kk = 0; kk < 4; ++kk) {
          int c = wid * 8 + k0 + kk;
          h0[kk] = hpre[c * NP + lane];
          h1[kk] = hpre[c * NP + lane + 64];
        }
      }
      float2 A[4], B[4];
#pragma unroll
      for (int kk = 0; kk < 4; ++kk) {
        int c = wid * 8 + k0 + kk;
        A[kk] = fld[lane * LSTR + c];
        B[kk] = fld[(lane + 64) * LSTR + c];
      }
#pragma unroll
      for (int kk = 0; kk < 4; ++kk) dif128(A[kk], B[kk], tw);
#pragma unroll
      for (int kk = 0; kk < 4; ++kk) {
        int c = wid * 8 + k0 + kk;
        if (mode == 0) {
          int kxc = br7(c);
          float fx = (float)(kxc < 64 ? kxc : kxc - 128) * (1.f / 128.f);
          float com = fx * sh1;
          float s0, c0, s1, c1;
          __sincosf(-6.28318530717959f * (fy0 * sh0 + com), &s0, &c0);
          __sincosf(-6.28318530717959f * (fy1 * sh0 + com), &s1, &c1);
          cmul(A[kk], c0 * INV_N2, s0 * INV_N2);
          cmul(B[kk], c1 * INV_N2, s1 * INV_N2);
        } else if (use_hpre) {
          cmul(A[kk], h0[kk].x, h0[kk].y);
          cmul(B[kk], h1[kk].x, h1[kk].y);
        } else {
          int kx = br7(c), ky0 = br7(lane);
          float hr0 = H[(ky0 * NP + kx) * 2], hi0 = H[(ky0 * NP + kx) * 2 + 1];
          float hr1 = H[((ky0 + 1) * NP + kx) * 2], hi1 = H[((ky0 + 1) * NP + kx) * 2 + 1];
          cmul(A[kk], hr0 * INV_N2, hi0 * INV_N2);
          cmul(B[kk], hr1 * INV_N2, hi1 * INV_N2);
        }
      }
#pragma unroll
      for (int kk = 0; kk < 4; ++kk) dit128(A[kk], B[kk], tw);
#pragma unroll
      for (int kk = 0; kk < 4; ++kk) {
        int c = wid * 8 + k0 + kk;
        fld[lane * LSTR + c]        = A[kk];
        fld[(lane + 64) * LSTR + c] = B[kk];
      }
    }
    __syncthreads();
  };

  // ---- row phase: invRow, multiply T(z), Frow ---------------------------
  auto rphase = [&](int z) {
#pragma unroll
    for (int k0 = 0; k0 < 8; k0 += 4) {
      int rr = wid * 8 + k0;
      float pa0[4], ph0[4], pa1[4], ph1[4];
#pragma unroll
      for (int kk = 0; kk < 4; ++kk) {
        size_t ob = ((size_t)(o * NZ + z) * NYX + (size_t)(cy + rr + kk)) * NYX + cx;
        pa0[kk] = obja[ob + lane];      ph0[kk] = objp[ob + lane];
        pa1[kk] = obja[ob + lane + 64]; ph1[kk] = objp[ob + lane + 64];
      }
      float2 A[4], B[4];
#pragma unroll
      for (int kk = 0; kk < 4; ++kk) {
        int base = (rr + kk) * LSTR;
        A[kk] = fld[base + lane];
        B[kk] = fld[base + lane + 64];
      }
#pragma unroll
      for (int kk = 0; kk < 4; ++kk) dit128(A[kk], B[kk], tw);
#pragma unroll
      for (int kk = 0; kk < 4; ++kk) {
        float s0, c0, s1, c1;
        __sincosf(ph0[kk], &s0, &c0);
        __sincosf(ph1[kk], &s1, &c1);
        cmul(A[kk], pa0[kk] * c0, pa0[kk] * s0);
        cmul(B[kk], pa1[kk] * c1, pa1[kk] * s1);
      }
#pragma unroll
      for (int kk = 0; kk < 4; ++kk) dif128(A[kk], B[kk], tw);
#pragma unroll
      for (int kk = 0; kk < 4; ++kk) {
        int base = (rr + kk) * LSTR;
        fld[base + lane]      = A[kk];
        fld[base + lane + 64] = B[kk];
      }
    }
    __syncthreads();
  };

  cphase(0);        // Fcol + ramp + invCol  (completes probe shift)
  rphase(0);        // invRow + T0 + Frow
#pragma unroll 1
  for (int z = 1; z < NZ; ++z) {
    cphase(1);      // Fcol + H + invCol     (propagation z-1 -> z)
    rphase(z);      // invRow + Tz + Frow
  }

  // ---- final column FFT -> |.|^2 -> in-LDS bit-reversal reorder ---------
  float M0[8], M1[8];
#pragma unroll
  for (int k0 = 0; k0 < 8; k0 += 4) {
    float2 A[4], B[4];
#pragma unroll
    for (int kk = 0; kk < 4; ++kk) {
      int c = wid * 8 + k0 + kk;
      A[kk] = fld[lane * LSTR + c];
      B[kk] = fld[(lane + 64) * LSTR + c];
    }
#pragma unroll
    for (int kk = 0; kk < 4; ++kk) dif128(A[kk], B[kk], tw);
#pragma unroll
    for (int kk = 0; kk < 4; ++kk) {
      M0[k0 + kk] = (A[kk].x * A[kk].x + A[kk].y * A[kk].y) * wocc;
      M1[k0 + kk] = (B[kk].x * B[kk].x + B[kk].y * B[kk].y) * wocc;
    }
  }
  __syncthreads();   // all waves done reading the field
  {
    int r0 = br7(lane) * FSTR;   // rows br7(lane) and br7(lane)+1
#pragma unroll
    for (int k = 0; k < 8; ++k) {
      int bc = br7(wid * 8 + k);
      fl[r0 + bc]        = M0[k];
      fl[r0 + FSTR + bc] = M1[k];
    }
  }
  __syncthreads();
  // coalesced output: wave wid handles rows wid*8..wid*8+7
#pragma unroll
  for (int j = 0; j < 8; ++j) {
    int ky = wid * 8 + j;
    float v0 = fl[ky * FSTR + lane];
    float v1 = fl[ky * FSTR + lane + 64];
    if (use_part) {
      size_t base = (size_t)blk * (NP * NP) + ky * NP;
      part[base + lane]      = v0;
      part[base + lane + 64] = v1;
    } else {
      size_t base = (size_t)n * (NP * NP) + ky * NP;
      atomicAdd(&dp[base + lane],      v0);
      atomicAdd(&dp[base + lane + 64], v1);
    }
  }
}

extern "C" void kernel_launch(void* const* d_in, const int* in_sizes, int n_in,
                              void* d_out, int out_size, void* d_ws, size_t ws_size,
                              hipStream_t stream) {
  const float* obja   = (const float*)d_in[0];
  const float* objp   = (const float*)d_in[1];
  const float* probe  = (const float*)d_in[2];
  const float* shifts = (const float*)d_in[3];
  const float* H      = (const float*)d_in[4];
  const float* occu   = (const float*)d_in[5];
  const int*   indices = (const int*)d_in[6];
  const int*   crop    = (const int*)d_in[7];
  float* dp = (float*)d_out;

  const size_t part_bytes = (size_t)BATCH * OMODE * PMODE * NP * NP * sizeof(float); // 32 MB
  const size_t hpre_bytes = (size_t)NP * NP * sizeof(float2);                        // 128 KB

  int use_part = (ws_size >= part_bytes + hpre_bytes) ? 1 : 0;
  float* part = (float*)d_ws;
  float2* hpre;
  int use_hpre;
  if (use_part) {
    hpre = (float2*)((char*)d_ws + part_bytes);
    use_hpre = 1;
  } else {
    use_hpre = (ws_size >= hpre_bytes) ? 1 : 0;
    hpre = (float2*)d_ws;
  }

  if (!use_part) {
    // atomic fallback accumulates -> must zero output every call
    hipMemsetAsync(d_out, 0, (size_t)out_size * sizeof(float), stream);
  }
  if (use_hpre) {
    hipLaunchKernelGGL(init_hpre, dim3((NP * NP + 255) / 256), dim3(256), 0,
                       stream, H, hpre);
  }

  const int lds_bytes = NP * LSTR * (int)sizeof(float2);  // 132096
  hipFuncSetAttribute((const void*)ptycho_chain,
                      hipFuncAttributeMaxDynamicSharedMemorySize, lds_bytes);
  hipLaunchKernelGGL(ptycho_chain, dim3(BATCH * OMODE * PMODE), dim3(1024),
                     lds_bytes, stream,
                     obja, objp, probe, shifts, H, hpre, occu, indices, crop,
                     dp, part, use_hpre, use_part);
  if (use_part) {
    hipLaunchKernelGGL(reduce_dp, dim3((BATCH * NP * NP + 255) / 256), dim3(256),
                       0, stream, part, dp);
  }
}

// Round 4
// 599.234 us; speedup vs baseline: 1.6610x; 1.1650x over previous
//
#include <hip/hip_runtime.h>

// ---- problem constants --------------------------------------------------
static constexpr int OMODE = 2, PMODE = 4, NZ = 8;
static constexpr int NYX = 512;   // object plane 512x512
static constexpr int NP  = 128;   // probe / tile 128x128
static constexpr int BATCH = 64;
static constexpr int LSTR = 129;  // padded LDS line stride (float2 units)
static constexpr int FSTR = 131;  // padded stride for the output reorder (floats)
static constexpr float INV_N2 = 1.0f / 16384.0f;   // 1/(128*128) ifft2 norm

__device__ __forceinline__ int br7(int x) { return (int)(__brev((unsigned)x) >> 25); }

// ---- cross-lane exchange: DPP / permlane / swizzle ----------------------
template<int CTRL>
__device__ __forceinline__ float dppf(float x) {
  int i = __float_as_int(x);
  int r = __builtin_amdgcn_update_dpp(i, i, CTRL, 0xF, 0xF, false);
  return __int_as_float(r);
}

// partner value at lane^H for all 64 lanes
// permlane{16,32}_swap(a,b): new_a = {a.lo, b.lo}, new_b = {a.hi, b.hi}
// (lower half of VSRC swaps with upper half of VDST). With a==b==u:
//   r[0] = {u.lo, u.lo}, r[1] = {u.hi, u.hi}
// -> partner for a LOWER-half lane is r[1][lane], for an UPPER-half lane r[0][lane].
template<int H>
__device__ __forceinline__ float shx(float x, int lane) {
  if constexpr (H == 1) {
    return dppf<0xB1>(x);                       // quad_perm [1,0,3,2]
  } else if constexpr (H == 2) {
    return dppf<0x4E>(x);                       // quad_perm [2,3,0,1]
  } else if constexpr (H == 4) {
    return __int_as_float(__builtin_amdgcn_ds_swizzle(__float_as_int(x), 0x101F));
  } else if constexpr (H == 8) {
    return dppf<0x128>(x);                      // row_ror:8 == xor 8 within row16
  } else if constexpr (H == 16) {
#if __has_builtin(__builtin_amdgcn_permlane16_swap)
    unsigned u = __float_as_uint(x);
    auto r = __builtin_amdgcn_permlane16_swap(u, u, false, false);
    return __uint_as_float(((lane >> 4) & 1) ? r[0] : r[1]);   // odd row16 -> r0, even -> r1
#else
    return __shfl_xor(x, 16);
#endif
  } else {  // H == 32
#if __has_builtin(__builtin_amdgcn_permlane32_swap)
    unsigned u = __float_as_uint(x);
    auto r = __builtin_amdgcn_permlane32_swap(u, u, false, false);
    return __uint_as_float((lane >> 5) ? r[0] : r[1]);         // upper half -> r0, lower -> r1
#else
    return __shfl_xor(x, 32);
#endif
  }
}

// Per-thread twiddles, compile-time indexed only -> VGPRs.
struct Tw {
  float tc[7], ts[7];        // cos/sin(pi*j/h), j=lane&(h-1), h=1<<s
  float g[6];                // +1 lower lane of pair, -1 upper
  float dwr[6], dwi[6];      // DIF post-mul: up ? conj(w) : 1   (DIT uses dwr,-dwi)
};

__device__ __forceinline__ void cmul(float2& a, float br_, float bi_) {
  float x = a.x * br_ - a.y * bi_;
  a.y = a.x * bi_ + a.y * br_;
  a.x = x;
}

template<int S>
__device__ __forceinline__ void dif_stage(float2& A, float2& B, const Tw& tw, int lane) {
  constexpr int H = 1 << S;
  float tx, ty, dx, dy;
  tx = shx<H>(A.x, lane); ty = shx<H>(A.y, lane);
  dx = tx + tw.g[S] * A.x; dy = ty + tw.g[S] * A.y;
  A.x = dx * tw.dwr[S] - dy * tw.dwi[S];
  A.y = dx * tw.dwi[S] + dy * tw.dwr[S];
  tx = shx<H>(B.x, lane); ty = shx<H>(B.y, lane);
  dx = tx + tw.g[S] * B.x; dy = ty + tw.g[S] * B.y;
  B.x = dx * tw.dwr[S] - dy * tw.dwi[S];
  B.y = dx * tw.dwi[S] + dy * tw.dwr[S];
}

template<int S>
__device__ __forceinline__ void dit_stage(float2& A, float2& B, const Tw& tw, int lane) {
  constexpr int H = 1 << S;
  float mx, my, tx, ty;
  mx =  A.x * tw.dwr[S] + A.y * tw.dwi[S];
  my = -A.x * tw.dwi[S] + A.y * tw.dwr[S];
  tx = shx<H>(mx, lane); ty = shx<H>(my, lane);
  A.x = tx + tw.g[S] * mx; A.y = ty + tw.g[S] * my;
  mx =  B.x * tw.dwr[S] + B.y * tw.dwi[S];
  my = -B.x * tw.dwi[S] + B.y * tw.dwr[S];
  tx = shx<H>(mx, lane); ty = shx<H>(my, lane);
  B.x = tx + tw.g[S] * mx; B.y = ty + tw.g[S] * my;
}

// Forward 128-pt DIF across 64 lanes, 2 complex/lane (slots: lane, lane+64).
// Natural-order input -> bit-reversed-order output slots.
__device__ __forceinline__ void dif128(float2& A, float2& B, const Tw& tw, int lane) {
  { // register stage h=64: w = e^{-i*pi*lane/64}
    float dr = A.x - B.x, di = A.y - B.y;
    A.x += B.x; A.y += B.y;
    B.x = dr * tw.tc[6] + di * tw.ts[6];
    B.y = di * tw.tc[6] - dr * tw.ts[6];
  }
  dif_stage<5>(A, B, tw, lane);
  dif_stage<4>(A, B, tw, lane);
  dif_stage<3>(A, B, tw, lane);
  dif_stage<2>(A, B, tw, lane);
  dif_stage<1>(A, B, tw, lane);
  dif_stage<0>(A, B, tw, lane);
}

// Inverse (unnormalized) 128-pt DIT: bit-reversed input slots -> natural output.
__device__ __forceinline__ void dit128(float2& A, float2& B, const Tw& tw, int lane) {
  dit_stage<0>(A, B, tw, lane);
  dit_stage<1>(A, B, tw, lane);
  dit_stage<2>(A, B, tw, lane);
  dit_stage<3>(A, B, tw, lane);
  dit_stage<4>(A, B, tw, lane);
  dit_stage<5>(A, B, tw, lane);
  { // register stage h=64: w = e^{+i*pi*lane/64}
    float mx = B.x * tw.tc[6] - B.y * tw.ts[6];
    float my = B.x * tw.ts[6] + B.y * tw.tc[6];
    B.x = A.x - mx; B.y = A.y - my;
    A.x += mx; A.y += my;
  }
}

// Pre-scramble H into workspace: hp[px][py] = H[br(py)][br(px)] * (1/N^2).
__global__ void __launch_bounds__(256) init_hpre(const float* __restrict__ H,
                                                 float2* __restrict__ hp) {
  int i = blockIdx.x * blockDim.x + threadIdx.x;
  if (i >= NP * NP) return;
  int px = i >> 7, py = i & (NP - 1);
  int ky = br7(py), kx = br7(px);
  hp[px * NP + py] = make_float2(H[(ky * NP + kx) * 2 + 0] * INV_N2,
                                 H[(ky * NP + kx) * 2 + 1] * INV_N2);
}

// Sum the 8 (o,p) partials per batch element.
__global__ void __launch_bounds__(256) reduce_dp(const float* __restrict__ part,
                                                 float* __restrict__ dp) {
  int i = blockIdx.x * 256 + threadIdx.x;
  if (i >= BATCH * NP * NP) return;
  int n = i >> 14;
  int r = i & (NP * NP - 1);
  const float* b = part + (size_t)n * 8 * (NP * NP) + r;
  float s = 0.f;
#pragma unroll
  for (int j = 0; j < 8; ++j) s += b[(size_t)j * (NP * NP)];
  dp[i] = s;
}

__global__ void __launch_bounds__(1024, 4) ptycho_chain(
    const float* __restrict__ obja, const float* __restrict__ objp,
    const float* __restrict__ probe, const float* __restrict__ shifts,
    const float* __restrict__ H, const float2* __restrict__ hpre,
    const float* __restrict__ occu, const int* __restrict__ indices,
    const int* __restrict__ crop, float* __restrict__ dp,
    float* __restrict__ part, int use_hpre, int use_part)
{
  extern __shared__ float2 fld[];          // [128][LSTR] interleaved re/im
  float* fl = (float*)fld;                 // raw view for the output reorder

  const int blk  = blockIdx.x;             // n*8 + o*4 + p
  const int n    = blk >> 3;
  const int o    = (blk >> 2) & 1;
  const int p    = blk & 3;
  const int tid  = threadIdx.x;
  const int wid  = tid >> 6;               // 16 waves
  const int lane = tid & 63;

  const int   pos = indices[n];
  const int   cy  = crop[2 * pos + 0];
  const int   cx  = crop[2 * pos + 1];
  const float sh0 = shifts[2 * pos + 0];
  const float sh1 = shifts[2 * pos + 1];
  const float wocc = occu[o];

  // ---- twiddles ---------------------------------------------------------
  Tw tw;
#pragma unroll
  for (int s = 0; s < 7; ++s) {
    int h = 1 << s;
    int j = lane & (h - 1);
    float ang = 3.14159265358979f * (float)j / (float)h;
    __sincosf(ang, &tw.ts[s], &tw.tc[s]);
  }
#pragma unroll
  for (int s = 0; s < 6; ++s) {
    bool up = (lane >> s) & 1;
    tw.g[s]   = up ? -1.f : 1.f;
    tw.dwr[s] = up ? tw.tc[s] : 1.f;
    tw.dwi[s] = up ? -tw.ts[s] : 0.f;
  }

  // fftfreq at bit-reversed slot positions for this lane's two slots
  float fy0, fy1;
  {
    int k0 = br7(lane);                 // even
    fy0 = (float)(k0 < 64 ? k0 : k0 - 128) * (1.f / 128.f);
    int k1 = k0 + 1;
    fy1 = (float)(k1 < 64 ? k1 : k1 - 128) * (1.f / 128.f);
  }

  // ---- P0: load probe rows + forward row FFT ----------------------------
  const float2* probe2 = (const float2*)probe;
#pragma unroll
  for (int k0 = 0; k0 < 8; k0 += 4) {
    float2 A[4], B[4];
#pragma unroll
    for (int kk = 0; kk < 4; ++kk) {
      int r = wid * 8 + k0 + kk;
      A[kk] = probe2[(p * NP + r) * NP + lane];
      B[kk] = probe2[(p * NP + r) * NP + lane + 64];
    }
#pragma unroll
    for (int kk = 0; kk < 4; ++kk) dif128(A[kk], B[kk], tw, lane);
#pragma unroll
    for (int kk = 0; kk < 4; ++kk) {
      int base = (wid * 8 + k0 + kk) * LSTR;
      fld[base + lane]      = A[kk];
      fld[base + lane + 64] = B[kk];
    }
  }
  __syncthreads();

  // ---- column phase: Fcol, freq multiply, invCol ------------------------
  auto cphase = [&](int mode) {
#pragma unroll
    for (int k0 = 0; k0 < 8; k0 += 4) {
      float2 h0[4], h1[4];
      if (mode == 1 && use_hpre) {
#pragma unroll
        for (int kk = 0; kk < 4; ++kk) {
          int c = wid * 8 + k0 + kk;
          h0[kk] = hpre[c * NP + lane];
          h1[kk] = hpre[c * NP + lane + 64];
        }
      }
      float2 A[4], B[4];
#pragma unroll
      for (int kk = 0; kk < 4; ++kk) {
        int c = wid * 8 + k0 + kk;
        A[kk] = fld[lane * LSTR + c];
        B[kk] = fld[(lane + 64) * LSTR + c];
      }
#pragma unroll
      for (int kk = 0; kk < 4; ++kk) dif128(A[kk], B[kk], tw, lane);
#pragma unroll
      for (int kk = 0; kk < 4; ++kk) {
        int c = wid * 8 + k0 + kk;
        if (mode == 0) {
          int kxc = br7(c);
          float fx = (float)(kxc < 64 ? kxc : kxc - 128) * (1.f / 128.f);
          float com = fx * sh1;
          float s0, c0, s1, c1;
          __sincosf(-6.28318530717959f * (fy0 * sh0 + com), &s0, &c0);
          __sincosf(-6.28318530717959f * (fy1 * sh0 + com), &s1, &c1);
          cmul(A[kk], c0 * INV_N2, s0 * INV_N2);
          cmul(B[kk], c1 * INV_N2, s1 * INV_N2);
        } else if (use_hpre) {
          cmul(A[kk], h0[kk].x, h0[kk].y);
          cmul(B[kk], h1[kk].x, h1[kk].y);
        } else {
          int kx = br7(c), ky0 = br7(lane);
          float hr0 = H[(ky0 * NP + kx) * 2], hi0 = H[(ky0 * NP + kx) * 2 + 1];
          float hr1 = H[((ky0 + 1) * NP + kx) * 2], hi1 = H[((ky0 + 1) * NP + kx) * 2 + 1];
          cmul(A[kk], hr0 * INV_N2, hi0 * INV_N2);
          cmul(B[kk], hr1 * INV_N2, hi1 * INV_N2);
        }
      }
#pragma unroll
      for (int kk = 0; kk < 4; ++kk) dit128(A[kk], B[kk], tw, lane);
#pragma unroll
      for (int kk = 0; kk < 4; ++kk) {
        int c = wid * 8 + k0 + kk;
        fld[lane * LSTR + c]        = A[kk];
        fld[(lane + 64) * LSTR + c] = B[kk];
      }
    }
    __syncthreads();
  };

  // ---- row phase: invRow, multiply T(z), Frow ---------------------------
  auto rphase = [&](int z) {
#pragma unroll
    for (int k0 = 0; k0 < 8; k0 += 4) {
      int rr = wid * 8 + k0;
      float pa0[4], ph0[4], pa1[4], ph1[4];
#pragma unroll
      for (int kk = 0; kk < 4; ++kk) {
        size_t ob = ((size_t)(o * NZ + z) * NYX + (size_t)(cy + rr + kk)) * NYX + cx;
        pa0[kk] = obja[ob + lane];      ph0[kk] = objp[ob + lane];
        pa1[kk] = obja[ob + lane + 64]; ph1[kk] = objp[ob + lane + 64];
      }
      float2 A[4], B[4];
#pragma unroll
      for (int kk = 0; kk < 4; ++kk) {
        int base = (rr + kk) * LSTR;
        A[kk] = fld[base + lane];
        B[kk] = fld[base + lane + 64];
      }
#pragma unroll
      for (int kk = 0; kk < 4; ++kk) dit128(A[kk], B[kk], tw, lane);
#pragma unroll
      for (int kk = 0; kk < 4; ++kk) {
        float s0, c0, s1, c1;
        __sincosf(ph0[kk], &s0, &c0);
        __sincosf(ph1[kk], &s1, &c1);
        cmul(A[kk], pa0[kk] * c0, pa0[kk] * s0);
        cmul(B[kk], pa1[kk] * c1, pa1[kk] * s1);
      }
#pragma unroll
      for (int kk = 0; kk < 4; ++kk) dif128(A[kk], B[kk], tw, lane);
#pragma unroll
      for (int kk = 0; kk < 4; ++kk) {
        int base = (rr + kk) * LSTR;
        fld[base + lane]      = A[kk];
        fld[base + lane + 64] = B[kk];
      }
    }
    __syncthreads();
  };

  cphase(0);        // Fcol + ramp + invCol  (completes probe shift)
  rphase(0);        // invRow + T0 + Frow
#pragma unroll 1
  for (int z = 1; z < NZ; ++z) {
    cphase(1);      // Fcol + H + invCol     (propagation z-1 -> z)
    rphase(z);      // invRow + Tz + Frow
  }

  // ---- final column FFT -> |.|^2 -> in-LDS bit-reversal reorder ---------
  float M0[8], M1[8];
#pragma unroll
  for (int k0 = 0; k0 < 8; k0 += 4) {
    float2 A[4], B[4];
#pragma unroll
    for (int kk = 0; kk < 4; ++kk) {
      int c = wid * 8 + k0 + kk;
      A[kk] = fld[lane * LSTR + c];
      B[kk] = fld[(lane + 64) * LSTR + c];
    }
#pragma unroll
    for (int kk = 0; kk < 4; ++kk) dif128(A[kk], B[kk], tw, lane);
#pragma unroll
    for (int kk = 0; kk < 4; ++kk) {
      M0[k0 + kk] = (A[kk].x * A[kk].x + A[kk].y * A[kk].y) * wocc;
      M1[k0 + kk] = (B[kk].x * B[kk].x + B[kk].y * B[kk].y) * wocc;
    }
  }
  __syncthreads();   // all waves done reading the field
  {
    int r0 = br7(lane) * FSTR;   // rows br7(lane) and br7(lane)+1
#pragma unroll
    for (int k = 0; k < 8; ++k) {
      int bc = br7(wid * 8 + k);
      fl[r0 + bc]        = M0[k];
      fl[r0 + FSTR + bc] = M1[k];
    }
  }
  __syncthreads();
  // coalesced output: wave wid handles rows wid*8..wid*8+7
#pragma unroll
  for (int j = 0; j < 8; ++j) {
    int ky = wid * 8 + j;
    float v0 = fl[ky * FSTR + lane];
    float v1 = fl[ky * FSTR + lane + 64];
    if (use_part) {
      size_t base = (size_t)blk * (NP * NP) + ky * NP;
      part[base + lane]      = v0;
      part[base + lane + 64] = v1;
    } else {
      size_t base = (size_t)n * (NP * NP) + ky * NP;
      atomicAdd(&dp[base + lane],      v0);
      atomicAdd(&dp[base + lane + 64], v1);
    }
  }
}

extern "C" void kernel_launch(void* const* d_in, const int* in_sizes, int n_in,
                              void* d_out, int out_size, void* d_ws, size_t ws_size,
                              hipStream_t stream) {
  const float* obja   = (const float*)d_in[0];
  const float* objp   = (const float*)d_in[1];
  const float* probe  = (const float*)d_in[2];
  const float* shifts = (const float*)d_in[3];
  const float* H      = (const float*)d_in[4];
  const float* occu   = (const float*)d_in[5];
  const int*   indices = (const int*)d_in[6];
  const int*   crop    = (const int*)d_in[7];
  float* dp = (float*)d_out;

  const size_t part_bytes = (size_t)BATCH * OMODE * PMODE * NP * NP * sizeof(float); // 32 MB
  const size_t hpre_bytes = (size_t)NP * NP * sizeof(float2);                        // 128 KB

  int use_part = (ws_size >= part_bytes + hpre_bytes) ? 1 : 0;
  float* part = (float*)d_ws;
  float2* hpre;
  int use_hpre;
  if (use_part) {
    hpre = (float2*)((char*)d_ws + part_bytes);
    use_hpre = 1;
  } else {
    use_hpre = (ws_size >= hpre_bytes) ? 1 : 0;
    hpre = (float2*)d_ws;
  }

  if (!use_part) {
    // atomic fallback accumulates -> must zero output every call
    hipMemsetAsync(d_out, 0, (size_t)out_size * sizeof(float), stream);
  }
  if (use_hpre) {
    hipLaunchKernelGGL(init_hpre, dim3((NP * NP + 255) / 256), dim3(256), 0,
                       stream, H, hpre);
  }

  const int lds_bytes = NP * LSTR * (int)sizeof(float2);  // 132096
  hipFuncSetAttribute((const void*)ptycho_chain,
                      hipFuncAttributeMaxDynamicSharedMemorySize, lds_bytes);
  hipLaunchKernelGGL(ptycho_chain, dim3(BATCH * OMODE * PMODE), dim3(1024),
                     lds_bytes, stream,
                     obja, objp, probe, shifts, H, hpre, occu, indices, crop,
                     dp, part, use_hpre, use_part);
  if (use_part) {
    hipLaunchKernelGGL(reduce_dp, dim3((BATCH * NP * NP + 255) / 256), dim3(256),
                       0, stream, part, dp);
  }
}